// Round 1
// baseline (749.453 us; speedup 1.0000x reference)
//
#include <hip/hip_runtime.h>
#include <stdint.h>

#define BATCH 8192
#define IN_F  4096
#define OUT_F 4096

#define BM 256
#define BN 256
#define BK 64
#define KT (IN_F / BK)   // 64 k-tiles

typedef __attribute__((ext_vector_type(8))) short bf16x8;   // 8 bf16 = 4 VGPRs
typedef __attribute__((ext_vector_type(4))) float f32x4;    // 16x16 MFMA acc

// ---------- helpers ----------

__device__ __forceinline__ unsigned short f2bf(float f) {
    // round-to-nearest-even bf16 (inputs finite)
    unsigned int u = __float_as_uint(f);
    unsigned int lsb = (u >> 16) & 1u;
    u += 0x7fffu + lsb;
    return (unsigned short)(u >> 16);
}

__device__ __forceinline__ void gl_lds16(const void* g, void* l) {
    // async global->LDS, 16B per lane. HW dest = wave-uniform base + lane*16.
    __builtin_amdgcn_global_load_lds(
        (const __attribute__((address_space(1))) void*)g,
        (__attribute__((address_space(3))) void*)l,
        16, 0, 0);
}

// ---------- fused convert kernel (unit-stride: 1 float4 in, 4 bf16 out) ----------
#define XF4 (BATCH * IN_F / 4)   // 8388608
#define WF4 (OUT_F * IN_F / 4)   // 4194304

__global__ __launch_bounds__(256) void cvt_kernel(const float4* __restrict__ x,
                                                  const float4* __restrict__ w,
                                                  const float4* __restrict__ m,
                                                  uint2* __restrict__ xo,
                                                  uint2* __restrict__ wo) {
    const int i = blockIdx.x * 256 + threadIdx.x;
    union { unsigned short u[4]; uint2 v; } r;
    if (i < XF4) {
        const float4 a = x[i];
        r.u[0] = f2bf(a.x); r.u[1] = f2bf(a.y);
        r.u[2] = f2bf(a.z); r.u[3] = f2bf(a.w);
        xo[i] = r.v;
    } else {
        const int j = i - XF4;
        const float4 a = w[j];
        const float4 b = m[j];
        r.u[0] = f2bf(a.x * b.x); r.u[1] = f2bf(a.y * b.y);
        r.u[2] = f2bf(a.z * b.z); r.u[3] = f2bf(a.w * b.w);
        wo[j] = r.v;
    }
}

// ---------- GEMM: C[M,N] = A[M,K] * W[N,K]^T + bias ----------
// 256x256 tile, BK=64, 8 waves (2Mx4N), per-wave 128x64 output, 16x16x32 MFMA.
// 8-phase-style schedule: per K-tile, 4 quadrant phases of
//   {12x ds_read_b128 ; s_barrier ; lgkmcnt(0) ; setprio(1) 16x MFMA setprio(0) ; s_barrier}
// Double-buffered LDS (2 x 64KiB), deep prefetch: tile t+2's 8 global_load_lds
// issued at end of iter t; one counted s_waitcnt vmcnt(8) per K-tile (never 0
// in the main loop).  LDS st_16x32 swizzle (byte ^= ((byte>>9)&1)<<5) applied
// on the ds_read side and inverted on the global source (gl_lds dest stays
// linear per m104/m173).
__global__ __launch_bounds__(512, 2) void gemm_kernel(const unsigned short* __restrict__ A,
                                                      const unsigned short* __restrict__ W,
                                                      const float* __restrict__ bias,
                                                      float* __restrict__ C) {
    __shared__ unsigned short lA[2][2][128 * BK];   // [buf][half][128 rows x 64 cols] = 64 KiB
    __shared__ unsigned short lB[2][2][128 * BK];   // 64 KiB  -> 128 KiB total

    const int tid  = threadIdx.x;
    const int lane = tid & 63;
    const int wave = tid >> 6;     // 0..7
    const int wm   = wave >> 2;    // 0..1  (M half)
    const int wn   = wave & 3;     // 0..3  (N quarter)

    // XCD-aware swizzle: 512 wgs, 64 contiguous per XCD
    const int wg = ((blockIdx.x & 7) << 6) | (blockIdx.x >> 3);
    const int bm = wg >> 4;        // 0..31
    const int bn = wg & 15;        // 0..15

    const int r15 = lane & 15;     // fragment row within 16
    const int g   = lane >> 4;     // k-group 0..3 (8 bf16 each)
    // swizzle XOR bit for reads: (row>>2)&1 == (r15>>2)&1 (all frag bases are x16)
    const int kx    = ((r15 >> 2) & 1) << 5;
    const int koff0 = (g * 16) ^ kx;          // byte offset in k for ks=0; ks adds 64

    // ---- staging geometry (per thread; same for A and B) ----
    // phys slot s = i*512+tid -> half = s>>10, sl = s&1023, LDS byte = sl*16.
    // inverse swizzle: row = sl>>3, stored chunk holds logical chunk
    // (sl&7) ^ (((sl>>5)&1)<<1)
    int hf[4], ldso[4];
    const unsigned short* gA[4];
    const unsigned short* gB[4];
#pragma unroll
    for (int i = 0; i < 4; ++i) {
        const int s    = i * 512 + tid;
        const int h    = s >> 10;
        const int sl   = s & 1023;
        const int row  = sl >> 3;
        const int chnk = (sl & 7) ^ (((sl >> 5) & 1) << 1);
        hf[i]   = h;
        ldso[i] = sl * 8;   // ushort units (16B per slot)
        gA[i] = A + (size_t)(bm * BM + h * 128 + row) * IN_F + chnk * 8;
        gB[i] = W + (size_t)(bn * BN + h * 128 + row) * IN_F + chnk * 8;
    }

#define STAGE(buf, ktn)                                                 \
    do {                                                                \
        _Pragma("unroll")                                               \
        for (int i = 0; i < 4; ++i) {                                   \
            gl_lds16(gA[i] + (ktn) * BK, &lA[buf][hf[i]][ldso[i]]);     \
            gl_lds16(gB[i] + (ktn) * BK, &lB[buf][hf[i]][ldso[i]]);     \
        }                                                               \
    } while (0)

    f32x4 acc[8][4] = {};

    STAGE(0, 0);          // 8 loads: tile 0
    STAGE(1, 1);          // 8 loads: tile 1

    int cur = 0;
    const int brl = (wn & 1) * 64;   // B row base within its half

    for (int kt = 0; kt < KT; ++kt) {
        // wait for THIS tile only; tile kt+1's 8 loads stay in flight
        if (kt + 1 < KT) { asm volatile("s_waitcnt vmcnt(8)" ::: "memory"); }
        else             { asm volatile("s_waitcnt vmcnt(0)" ::: "memory"); }
        __builtin_amdgcn_sched_barrier(0);
        __builtin_amdgcn_s_barrier();

        const char* aB = (const char*)&lA[cur][wm][0];
        const char* bB = (const char*)&lB[cur][wn >> 1][0];

#pragma unroll
        for (int p = 0; p < 4; ++p) {          // 4 quadrant phases
            const int qm = p >> 1;
            const int qn = p & 1;

            bf16x8 af[4][2], bg[2][2];
#pragma unroll
            for (int ks = 0; ks < 2; ++ks) {
#pragma unroll
                for (int fr = 0; fr < 4; ++fr)
                    af[fr][ks] = *(const bf16x8*)(aB +
                        (qm * 64 + fr * 16 + r15) * 128 + (koff0 + ks * 64));
#pragma unroll
                for (int fc = 0; fc < 2; ++fc)
                    bg[fc][ks] = *(const bf16x8*)(bB +
                        (brl + qn * 32 + fc * 16 + r15) * 128 + (koff0 + ks * 64));
            }
            __builtin_amdgcn_sched_barrier(0);
            __builtin_amdgcn_s_barrier();
            asm volatile("s_waitcnt lgkmcnt(0)" ::: "memory");
            __builtin_amdgcn_sched_barrier(0);

            __builtin_amdgcn_s_setprio(1);
#pragma unroll
            for (int ks = 0; ks < 2; ++ks)
#pragma unroll
                for (int fr = 0; fr < 4; ++fr)
#pragma unroll
                    for (int fc = 0; fc < 2; ++fc)
                        acc[qm * 4 + fr][qn * 2 + fc] =
                            __builtin_amdgcn_mfma_f32_16x16x32_bf16(
                                af[fr][ks], bg[fc][ks],
                                acc[qm * 4 + fr][qn * 2 + fc], 0, 0, 0);
            __builtin_amdgcn_s_setprio(0);
            __builtin_amdgcn_sched_barrier(0);
            __builtin_amdgcn_s_barrier();
        }

        // all reads of buf 'cur' completed (lgkmcnt(0) before each MFMA) and
        // barrier'd -> safe to overwrite with tile kt+2
        __builtin_amdgcn_sched_barrier(0);
        if (kt + 2 < KT) STAGE(cur, kt + 2);
        __builtin_amdgcn_sched_barrier(0);
        cur ^= 1;
    }
#undef STAGE

    // epilogue: 16x16 C/D layout: col = lane&15, row = (lane>>4)*4 + reg
    const int crow0 = bm * BM + wm * 128 + g * 4;
    const int ccol0 = bn * BN + wn * 64 + r15;
#pragma unroll
    for (int nf = 0; nf < 4; ++nf) {
        const int col = ccol0 + nf * 16;
        const float bj = bias[col];
#pragma unroll
        for (int mf = 0; mf < 8; ++mf)
#pragma unroll
            for (int reg = 0; reg < 4; ++reg) {
                const int row = crow0 + mf * 16 + reg;
                C[(size_t)row * OUT_F + col] = acc[mf][nf][reg] + bj;
            }
    }
}

// ---------- fallback (no workspace): correct-but-slow fp32 path ----------
__global__ __launch_bounds__(256) void fallback_kernel(const float* __restrict__ x,
                                                       const float* __restrict__ w,
                                                       const float* __restrict__ bias,
                                                       const float* __restrict__ m,
                                                       float* __restrict__ out) {
    size_t idx = (size_t)blockIdx.x * 256 + threadIdx.x;   // over BATCH*OUT_F
    int row = (int)(idx >> 12);        // / OUT_F
    int col = (int)(idx & (OUT_F - 1));
    const float4* xr = (const float4*)(x + (size_t)row * IN_F);
    const float4* wr = (const float4*)(w + (size_t)col * IN_F);
    const float4* mr = (const float4*)(m + (size_t)col * IN_F);
    float s = 0.f;
    for (int k = 0; k < IN_F / 4; ++k) {
        float4 xv = xr[k], wv = wr[k], mv = mr[k];
        s += xv.x * wv.x * mv.x + xv.y * wv.y * mv.y +
             xv.z * wv.z * mv.z + xv.w * wv.w * mv.w;
    }
    out[idx] = s + bias[col];
}

// ---------- launch ----------

extern "C" void kernel_launch(void* const* d_in, const int* in_sizes, int n_in,
                              void* d_out, int out_size, void* d_ws, size_t ws_size,
                              hipStream_t stream) {
    const float* x    = (const float*)d_in[0];
    const float* w    = (const float*)d_in[1];
    const float* bias = (const float*)d_in[2];
    const float* mask = (const float*)d_in[3];
    float* out = (float*)d_out;

    const size_t need = ((size_t)BATCH * IN_F + (size_t)OUT_F * IN_F) * sizeof(unsigned short);
    if (ws_size < need) {
        fallback_kernel<<<(size_t)BATCH * OUT_F / 256, 256, 0, stream>>>(
            x, w, bias, mask, out);
        return;
    }

    // workspace layout: x_bf16 [BATCH*IN_F] then w_bf16 [OUT_F*IN_F]
    unsigned short* xb = (unsigned short*)d_ws;
    unsigned short* wb = xb + (size_t)BATCH * IN_F;

    cvt_kernel<<<(XF4 + WF4) / 256, 256, 0, stream>>>(
        (const float4*)x, (const float4*)w, (const float4*)mask,
        (uint2*)xb, (uint2*)wb);

    gemm_kernel<<<512, 512, 0, stream>>>(xb, wb, bias, out);
}

// Round 2
// 664.840 us; speedup vs baseline: 1.1273x; 1.1273x over previous
//
#include <hip/hip_runtime.h>
#include <stdint.h>

#define BATCH 8192
#define IN_F  4096
#define OUT_F 4096

#define BM 256
#define BN 256
#define BK 64
#define KT (IN_F / BK)   // 64 k-tiles

typedef __attribute__((ext_vector_type(8))) short bf16x8;   // 8 bf16 = 4 VGPRs
typedef __attribute__((ext_vector_type(4))) float f32x4;    // 16x16 MFMA acc

// ---------- helpers ----------

__device__ __forceinline__ unsigned short f2bf(float f) {
    // round-to-nearest-even bf16 (inputs finite)
    unsigned int u = __float_as_uint(f);
    unsigned int lsb = (u >> 16) & 1u;
    u += 0x7fffu + lsb;
    return (unsigned short)(u >> 16);
}

__device__ __forceinline__ void gl_lds16(const void* g, void* l) {
    // async global->LDS, 16B per lane. HW dest = wave-uniform base + lane*16.
    __builtin_amdgcn_global_load_lds(
        (const __attribute__((address_space(1))) void*)g,
        (__attribute__((address_space(3))) void*)l,
        16, 0, 0);
}

// ---------- fused convert kernel (unit-stride: 1 float4 in, 4 bf16 out) ----------
#define XF4 (BATCH * IN_F / 4)   // 8388608
#define WF4 (OUT_F * IN_F / 4)   // 4194304

__global__ __launch_bounds__(256) void cvt_kernel(const float4* __restrict__ x,
                                                  const float4* __restrict__ w,
                                                  const float4* __restrict__ m,
                                                  uint2* __restrict__ xo,
                                                  uint2* __restrict__ wo) {
    const int i = blockIdx.x * 256 + threadIdx.x;
    union { unsigned short u[4]; uint2 v; } r;
    if (i < XF4) {
        const float4 a = x[i];
        r.u[0] = f2bf(a.x); r.u[1] = f2bf(a.y);
        r.u[2] = f2bf(a.z); r.u[3] = f2bf(a.w);
        xo[i] = r.v;
    } else {
        const int j = i - XF4;
        const float4 a = w[j];
        const float4 b = m[j];
        r.u[0] = f2bf(a.x * b.x); r.u[1] = f2bf(a.y * b.y);
        r.u[2] = f2bf(a.z * b.z); r.u[3] = f2bf(a.w * b.w);
        wo[j] = r.v;
    }
}

// ---------- GEMM: C[M,N] = A[M,K] * W[N,K]^T + bias ----------
// 256x256 tile, BK=64, 8 waves (2Mx4N), per-wave 128x64 output, 16x16x32 MFMA.
// LDS swizzle: stored 16B chunk = logical chunk ^ (row&7) (full 8-way spread ->
// conflict-free ds_read_b128 for the fragment pattern: 64 lanes hit all 32
// banks, 8 lanes per 4-bank group = the 8-cycle minimum). Applied as inverse
// permutation on the global_load_lds SOURCE (dest stays linear, m104/m173) and
// the same XOR on the ds_read side.
// Per K-tile (minimal LDS traffic, no fragment re-reads = 24 ds_read_b128/wave):
//   phase 0: read B[4 nf][2 ks] (8) + A[0..1][2] (4); bar; lgkm0; 16 MFMA; bar;
//            STAGE_B(cur, kt+2)   <- lB fully consumed (B now in regs)
//   phase 1..3: read A[2p..2p+1][2] (4); bar; lgkm0; 16 MFMA; bar
//   after phase 3: STAGE_A(cur, kt+2)
// Counted vmcnt(8) once per K-tile (8 loads in flight across the whole iter).
__global__ __launch_bounds__(512, 2) void gemm_kernel(const unsigned short* __restrict__ A,
                                                      const unsigned short* __restrict__ W,
                                                      const float* __restrict__ bias,
                                                      float* __restrict__ C) {
    __shared__ unsigned short lA[2][2][128 * BK];   // [buf][half][128 rows x 64 cols] = 64 KiB
    __shared__ unsigned short lB[2][2][128 * BK];   // 64 KiB -> 128 KiB total

    const int tid  = threadIdx.x;
    const int lane = tid & 63;
    const int wave = tid >> 6;     // 0..7
    const int wm   = wave >> 2;    // 0..1  (M half)
    const int wn   = wave & 3;     // 0..3  (N quarter)

    // XCD-aware swizzle: 512 wgs, 64 contiguous per XCD (bijective)
    const int wg = ((blockIdx.x & 7) << 6) | (blockIdx.x >> 3);
    const int bm = wg >> 4;        // 0..31
    const int bn = wg & 15;        // 0..15

    const int r15 = lane & 15;     // fragment row within 16
    const int g   = lane >> 4;     // k-group 0..3 (8 bf16 each)
    // stored chunk for logical chunk (g + 4*ks) at row R (R&7 == r15&7):
    //   (g + 4*ks) ^ (r15&7) = (g ^ (r15&7)) ^ (ks*4)   [g<4 so g+4 = g^4]
    const int k0 = (g ^ (r15 & 7)) << 4;     // byte offset, ks=0; ks=1: k0 ^ 64

    // ---- staging geometry (per thread; same for A and B) ----
    // phys slot s = i*512+tid -> half = s>>10, sl = s&1023, LDS byte = sl*16,
    // row = sl>>3, stored chunk = sl&7 holds logical chunk (sl&7)^(row&7)
    int hf[4], ldso[4];
    const unsigned short* gA[4];
    const unsigned short* gB[4];
#pragma unroll
    for (int i = 0; i < 4; ++i) {
        const int s    = i * 512 + tid;
        const int h    = s >> 10;
        const int sl   = s & 1023;
        const int row  = sl >> 3;
        const int chnk = (sl & 7) ^ (row & 7);
        hf[i]   = h;
        ldso[i] = sl * 8;   // ushort units (16B per slot)
        gA[i] = A + (size_t)(bm * BM + h * 128 + row) * IN_F + chnk * 8;
        gB[i] = W + (size_t)(bn * BN + h * 128 + row) * IN_F + chnk * 8;
    }

#define STAGE_A(buf, ktn)                                               \
    do {                                                                \
        _Pragma("unroll")                                               \
        for (int i = 0; i < 4; ++i)                                     \
            gl_lds16(gA[i] + (ktn) * BK, &lA[buf][hf[i]][ldso[i]]);     \
    } while (0)
#define STAGE_B(buf, ktn)                                               \
    do {                                                                \
        _Pragma("unroll")                                               \
        for (int i = 0; i < 4; ++i)                                     \
            gl_lds16(gB[i] + (ktn) * BK, &lB[buf][hf[i]][ldso[i]]);     \
    } while (0)

    f32x4 acc[8][4] = {};

    STAGE_B(0, 0); STAGE_A(0, 0);     // tile 0: 8 loads
    STAGE_B(1, 1); STAGE_A(1, 1);     // tile 1: 8 loads

    int cur = 0;
    const int brl = (wn & 1) * 64;    // B row base within its half

    for (int kt = 0; kt < KT; ++kt) {
        // wait for THIS tile's 8 loads; next tile's 8 stay in flight
        if (kt + 1 < KT) { asm volatile("s_waitcnt vmcnt(8)" ::: "memory"); }
        else             { asm volatile("s_waitcnt vmcnt(0)" ::: "memory"); }
        __builtin_amdgcn_sched_barrier(0);
        __builtin_amdgcn_s_barrier();

        const char* aB = (const char*)&lA[cur][wm][0];
        const char* bB = (const char*)&lB[cur][wn >> 1][0];

        // ---- phase 0: all B fragments (resident for the whole tile) + A[0..1]
        bf16x8 bg[4][2], af[2][2];
#pragma unroll
        for (int nf = 0; nf < 4; ++nf)
#pragma unroll
            for (int ks = 0; ks < 2; ++ks)
                bg[nf][ks] = *(const bf16x8*)(bB +
                    ((brl + nf * 16 + r15) << 7) + (k0 ^ (ks << 6)));
#pragma unroll
        for (int i = 0; i < 2; ++i)
#pragma unroll
            for (int ks = 0; ks < 2; ++ks)
                af[i][ks] = *(const bf16x8*)(aB +
                    ((i * 16 + r15) << 7) + (k0 ^ (ks << 6)));
        __builtin_amdgcn_sched_barrier(0);
        __builtin_amdgcn_s_barrier();
        asm volatile("s_waitcnt lgkmcnt(0)" ::: "memory");
        __builtin_amdgcn_sched_barrier(0);

        __builtin_amdgcn_s_setprio(1);
#pragma unroll
        for (int ks = 0; ks < 2; ++ks)
#pragma unroll
            for (int i = 0; i < 2; ++i)
#pragma unroll
                for (int nf = 0; nf < 4; ++nf)
                    acc[i][nf] = __builtin_amdgcn_mfma_f32_16x16x32_bf16(
                        af[i][ks], bg[nf][ks], acc[i][nf], 0, 0, 0);
        __builtin_amdgcn_s_setprio(0);
        __builtin_amdgcn_sched_barrier(0);
        __builtin_amdgcn_s_barrier();

        // lB[cur] fully consumed (B in registers) -> restage it now,
        // overlapping the 3 remaining compute phases
        if (kt + 2 < KT) STAGE_B(cur, kt + 2);
        __builtin_amdgcn_sched_barrier(0);

        // ---- phases 1..3: A[2p..2p+1], 16 MFMA each
#pragma unroll
        for (int pp = 1; pp < 4; ++pp) {
#pragma unroll
            for (int i = 0; i < 2; ++i)
#pragma unroll
                for (int ks = 0; ks < 2; ++ks)
                    af[i][ks] = *(const bf16x8*)(aB +
                        ((pp * 32 + i * 16 + r15) << 7) + (k0 ^ (ks << 6)));
            __builtin_amdgcn_sched_barrier(0);
            __builtin_amdgcn_s_barrier();
            asm volatile("s_waitcnt lgkmcnt(0)" ::: "memory");
            __builtin_amdgcn_sched_barrier(0);

            __builtin_amdgcn_s_setprio(1);
#pragma unroll
            for (int ks = 0; ks < 2; ++ks)
#pragma unroll
                for (int i = 0; i < 2; ++i)
#pragma unroll
                    for (int nf = 0; nf < 4; ++nf)
                        acc[pp * 2 + i][nf] = __builtin_amdgcn_mfma_f32_16x16x32_bf16(
                            af[i][ks], bg[nf][ks], acc[pp * 2 + i][nf], 0, 0, 0);
            __builtin_amdgcn_s_setprio(0);
            __builtin_amdgcn_sched_barrier(0);
            __builtin_amdgcn_s_barrier();
        }

        // all reads of lA[cur] done (phase3 lgkm0 + barrier) -> restage
        if (kt + 2 < KT) STAGE_A(cur, kt + 2);
        __builtin_amdgcn_sched_barrier(0);
        cur ^= 1;
    }
#undef STAGE_A
#undef STAGE_B

    // epilogue: 16x16 C/D layout: col = lane&15, row = (lane>>4)*4 + reg
    const int crow0 = bm * BM + wm * 128 + g * 4;
    const int ccol0 = bn * BN + wn * 64 + r15;
#pragma unroll
    for (int nf = 0; nf < 4; ++nf) {
        const int col = ccol0 + nf * 16;
        const float bj = bias[col];
#pragma unroll
        for (int mf = 0; mf < 8; ++mf)
#pragma unroll
            for (int reg = 0; reg < 4; ++reg) {
                const int row = crow0 + mf * 16 + reg;
                C[(size_t)row * OUT_F + col] = acc[mf][nf][reg] + bj;
            }
    }
}

// ---------- fallback (no workspace): correct-but-slow fp32 path ----------
__global__ __launch_bounds__(256) void fallback_kernel(const float* __restrict__ x,
                                                       const float* __restrict__ w,
                                                       const float* __restrict__ bias,
                                                       const float* __restrict__ m,
                                                       float* __restrict__ out) {
    size_t idx = (size_t)blockIdx.x * 256 + threadIdx.x;   // over BATCH*OUT_F
    int row = (int)(idx >> 12);        // / OUT_F
    int col = (int)(idx & (OUT_F - 1));
    const float4* xr = (const float4*)(x + (size_t)row * IN_F);
    const float4* wr = (const float4*)(w + (size_t)col * IN_F);
    const float4* mr = (const float4*)(m + (size_t)col * IN_F);
    float s = 0.f;
    for (int k = 0; k < IN_F / 4; ++k) {
        float4 xv = xr[k], wv = wr[k], mv = mr[k];
        s += xv.x * wv.x * mv.x + xv.y * wv.y * mv.y +
             xv.z * wv.z * mv.z + xv.w * wv.w * mv.w;
    }
    out[idx] = s + bias[col];
}

// ---------- launch ----------

extern "C" void kernel_launch(void* const* d_in, const int* in_sizes, int n_in,
                              void* d_out, int out_size, void* d_ws, size_t ws_size,
                              hipStream_t stream) {
    const float* x    = (const float*)d_in[0];
    const float* w    = (const float*)d_in[1];
    const float* bias = (const float*)d_in[2];
    const float* mask = (const float*)d_in[3];
    float* out = (float*)d_out;

    const size_t need = ((size_t)BATCH * IN_F + (size_t)OUT_F * IN_F) * sizeof(unsigned short);
    if (ws_size < need) {
        fallback_kernel<<<(size_t)BATCH * OUT_F / 256, 256, 0, stream>>>(
            x, w, bias, mask, out);
        return;
    }

    // workspace layout: x_bf16 [BATCH*IN_F] then w_bf16 [OUT_F*IN_F]
    unsigned short* xb = (unsigned short*)d_ws;
    unsigned short* wb = xb + (size_t)BATCH * IN_F;

    cvt_kernel<<<(XF4 + WF4) / 256, 256, 0, stream>>>(
        (const float4*)x, (const float4*)w, (const float4*)mask,
        (uint2*)xb, (uint2*)wb);

    gemm_kernel<<<512, 512, 0, stream>>>(xb, wb, bias, out);
}

// Round 3
// 582.546 us; speedup vs baseline: 1.2865x; 1.1413x over previous
//
#include <hip/hip_runtime.h>
#include <stdint.h>

#define BATCH 8192
#define IN_F  4096
#define OUT_F 4096

#define BM 256
#define BN 256
#define BK 64
#define KT (IN_F / BK)   // 64 k-tiles

typedef __attribute__((ext_vector_type(8))) short bf16x8;   // 8 bf16 = 4 VGPRs
typedef __attribute__((ext_vector_type(4))) float f32x4;    // 16x16 MFMA acc

// ---------- helpers ----------

__device__ __forceinline__ unsigned short f2bf(float f) {
    // round-to-nearest-even bf16 (inputs finite)
    unsigned int u = __float_as_uint(f);
    unsigned int lsb = (u >> 16) & 1u;
    u += 0x7fffu + lsb;
    return (unsigned short)(u >> 16);
}

__device__ __forceinline__ void gl_lds16(const void* g, void* l) {
    // async global->LDS, 16B per lane. HW dest = wave-uniform base + lane*16.
    __builtin_amdgcn_global_load_lds(
        (const __attribute__((address_space(1))) void*)g,
        (__attribute__((address_space(3))) void*)l,
        16, 0, 0);
}

// ---------- fused convert kernel (unit-stride: 1 float4 in, 4 bf16 out) ----------
#define XF4 (BATCH * IN_F / 4)   // 8388608
#define WF4 (OUT_F * IN_F / 4)   // 4194304

__global__ __launch_bounds__(256) void cvt_kernel(const float4* __restrict__ x,
                                                  const float4* __restrict__ w,
                                                  const float4* __restrict__ m,
                                                  uint2* __restrict__ xo,
                                                  uint2* __restrict__ wo) {
    const int i = blockIdx.x * 256 + threadIdx.x;
    union { unsigned short u[4]; uint2 v; } r;
    if (i < XF4) {
        const float4 a = x[i];
        r.u[0] = f2bf(a.x); r.u[1] = f2bf(a.y);
        r.u[2] = f2bf(a.z); r.u[3] = f2bf(a.w);
        xo[i] = r.v;
    } else {
        const int j = i - XF4;
        const float4 a = w[j];
        const float4 b = m[j];
        r.u[0] = f2bf(a.x * b.x); r.u[1] = f2bf(a.y * b.y);
        r.u[2] = f2bf(a.z * b.z); r.u[3] = f2bf(a.w * b.w);
        wo[j] = r.v;
    }
}

// ---------- GEMM: C[M,N] = A[M,K] * W[N,K]^T + bias ----------
// 256x256 tile, BK=64, 8 waves (2Mx4N), per-wave 128x64 output, 16x16x32 MFMA.
// LDS swizzle: stored 16B chunk = logical chunk ^ (row&7) -> conflict-free
// ds_read_b128 (verified: SQ_LDS_BANK_CONFLICT = 0).
// Schedule: register-level ping-pong at half-K-tile (ks-slice) granularity.
// Each slice = 12 ds_read_b128 (8 A-frag + 4 B-frag) + 32 MFMA.  While MFMA
// runs on reg set S_cur, the 12 reads for the next slice issue into S_next ->
// LDS serial time hides under the MFMA block.  ONE barrier per K-tile:
//   step1: read(S1 <- buf[cur], ks=1); MFMA(S0); lgkm0
//   vmcnt(0); s_barrier               // tile kt+1 visible, buf[cur] free
//   step2: read(S0 <- buf[cur^1], ks=0 of kt+1); STAGE(buf[cur], kt+2);
//          MFMA(S1); lgkm0
__global__ __launch_bounds__(512, 2) void gemm_kernel(const unsigned short* __restrict__ A,
                                                      const unsigned short* __restrict__ W,
                                                      const float* __restrict__ bias,
                                                      float* __restrict__ C) {
    __shared__ unsigned short lA[2][2][128 * BK];   // [buf][half][128 rows x 64 cols] = 64 KiB
    __shared__ unsigned short lB[2][2][128 * BK];   // 64 KiB -> 128 KiB total

    const int tid  = threadIdx.x;
    const int lane = tid & 63;
    const int wave = tid >> 6;     // 0..7
    const int wm   = wave >> 2;    // 0..1  (M half)
    const int wn   = wave & 3;     // 0..3  (N quarter)

    // XCD-aware swizzle: 512 wgs, 64 contiguous per XCD (bijective)
    const int wg = ((blockIdx.x & 7) << 6) | (blockIdx.x >> 3);
    const int bm = wg >> 4;        // 0..31
    const int bn = wg & 15;        // 0..15

    const int r15 = lane & 15;     // fragment row within 16
    const int g   = lane >> 4;     // k-group 0..3 (8 bf16 each)
    // stored chunk for logical chunk (g + 4*ks) at row R (R&7 == r15&7):
    //   (g ^ (r15&7)) ^ (ks*4)
    const int k0 = (g ^ (r15 & 7)) << 4;     // byte offset, ks=0; ks=1: k0 ^ 64

    // ---- staging geometry (per thread; same for A and B) ----
    // phys slot s = i*512+tid -> half = s>>10, sl = s&1023, LDS byte = sl*16,
    // row = sl>>3, stored chunk = sl&7 holds logical chunk (sl&7)^(row&7)
    int hf[4], ldso[4];
    const unsigned short* gA[4];
    const unsigned short* gB[4];
#pragma unroll
    for (int i = 0; i < 4; ++i) {
        const int s    = i * 512 + tid;
        const int h    = s >> 10;
        const int sl   = s & 1023;
        const int row  = sl >> 3;
        const int chnk = (sl & 7) ^ (row & 7);
        hf[i]   = h;
        ldso[i] = sl * 8;   // ushort units (16B per slot)
        gA[i] = A + (size_t)(bm * BM + h * 128 + row) * IN_F + chnk * 8;
        gB[i] = W + (size_t)(bn * BN + h * 128 + row) * IN_F + chnk * 8;
    }

#define STAGE_A(buf, ktn)                                               \
    do {                                                                \
        _Pragma("unroll")                                               \
        for (int i = 0; i < 4; ++i)                                     \
            gl_lds16(gA[i] + (ktn) * BK, &lA[buf][hf[i]][ldso[i]]);     \
    } while (0)
#define STAGE_B(buf, ktn)                                               \
    do {                                                                \
        _Pragma("unroll")                                               \
        for (int i = 0; i < 4; ++i)                                     \
            gl_lds16(gB[i] + (ktn) * BK, &lB[buf][hf[i]][ldso[i]]);     \
    } while (0)

    const int brl = (wn & 1) * 64;    // B row base within its half
    const char* aHalf = (const char*)&lA[0][wm][0];
    const char* bHalf = (const char*)&lB[0][wn >> 1][0];

#define READ_A(dst, curv, ks)                                               \
    do {                                                                    \
        _Pragma("unroll")                                                   \
        for (int mf = 0; mf < 8; ++mf)                                      \
            dst[mf] = *(const bf16x8*)(aHalf + (curv) * 32768 +             \
                        ((mf * 16 + r15) << 7) + (k0 ^ ((ks) << 6)));       \
    } while (0)
#define READ_B(dst, curv, ks)                                               \
    do {                                                                    \
        _Pragma("unroll")                                                   \
        for (int nf = 0; nf < 4; ++nf)                                      \
            dst[nf] = *(const bf16x8*)(bHalf + (curv) * 32768 +             \
                        ((brl + nf * 16 + r15) << 7) + (k0 ^ ((ks) << 6))); \
    } while (0)
#define MFMA_ALL(aa, bb)                                                    \
    do {                                                                    \
        __builtin_amdgcn_s_setprio(1);                                      \
        _Pragma("unroll")                                                   \
        for (int mf = 0; mf < 8; ++mf)                                      \
            _Pragma("unroll")                                               \
            for (int nf = 0; nf < 4; ++nf)                                  \
                acc[mf][nf] = __builtin_amdgcn_mfma_f32_16x16x32_bf16(      \
                    aa[mf], bb[nf], acc[mf][nf], 0, 0, 0);                  \
        __builtin_amdgcn_s_setprio(0);                                      \
    } while (0)

    f32x4 acc[8][4] = {};
    bf16x8 a0[8], b0[4], a1[8], b1[4];

    STAGE_B(0, 0); STAGE_A(0, 0);     // tile 0: 8 loads
    STAGE_B(1, 1); STAGE_A(1, 1);     // tile 1: 8 loads

    // tile 0 landed (newest 8 = tile 1 may stay in flight); cross-wave sync
    asm volatile("s_waitcnt vmcnt(8)" ::: "memory");
    __builtin_amdgcn_s_barrier();
    __builtin_amdgcn_sched_barrier(0);

    READ_B(b0, 0, 0); READ_A(a0, 0, 0);
    asm volatile("s_waitcnt lgkmcnt(0)" ::: "memory");
    __builtin_amdgcn_sched_barrier(0);

    int cur = 0;
    for (int kt = 0; kt < KT; ++kt) {
        // ---- step 1: issue reads of slice(kt,1); MFMA slice(kt,0) underneath
        READ_B(b1, cur, 1); READ_A(a1, cur, 1);
        MFMA_ALL(a0, b0);
        asm volatile("s_waitcnt lgkmcnt(0)" ::: "memory");
        __builtin_amdgcn_sched_barrier(0);

        if (kt + 1 < KT) {
            // all my tile-(kt+1) gl_lds retired; barrier -> visible to all
            // waves AND all waves done reading buf[cur]
            asm volatile("s_waitcnt vmcnt(0)" ::: "memory");
            __builtin_amdgcn_s_barrier();
            __builtin_amdgcn_sched_barrier(0);

            // ---- step 2: issue reads of slice(kt+1,0) + restage buf[cur]
            //      with tile kt+2; MFMA slice(kt,1) underneath
            const int nxt = cur ^ 1;
            READ_B(b0, nxt, 0); READ_A(a0, nxt, 0);
            if (kt + 2 < KT) { STAGE_B(cur, kt + 2); STAGE_A(cur, kt + 2); }
            MFMA_ALL(a1, b1);
            asm volatile("s_waitcnt lgkmcnt(0)" ::: "memory");
            __builtin_amdgcn_sched_barrier(0);
            cur = nxt;
        } else {
            MFMA_ALL(a1, b1);   // last slice
        }
    }
#undef STAGE_A
#undef STAGE_B
#undef READ_A
#undef READ_B
#undef MFMA_ALL

    // epilogue: 16x16 C/D layout: col = lane&15, row = (lane>>4)*4 + reg
    const int crow0 = bm * BM + wm * 128 + g * 4;
    const int ccol0 = bn * BN + wn * 64 + r15;
#pragma unroll
    for (int nf = 0; nf < 4; ++nf) {
        const int col = ccol0 + nf * 16;
        const float bj = bias[col];
#pragma unroll
        for (int mf = 0; mf < 8; ++mf)
#pragma unroll
            for (int reg = 0; reg < 4; ++reg) {
                const int row = crow0 + mf * 16 + reg;
                C[(size_t)row * OUT_F + col] = acc[mf][nf][reg] + bj;
            }
    }
}

// ---------- fallback (no workspace): correct-but-slow fp32 path ----------
__global__ __launch_bounds__(256) void fallback_kernel(const float* __restrict__ x,
                                                       const float* __restrict__ w,
                                                       const float* __restrict__ bias,
                                                       const float* __restrict__ m,
                                                       float* __restrict__ out) {
    size_t idx = (size_t)blockIdx.x * 256 + threadIdx.x;   // over BATCH*OUT_F
    int row = (int)(idx >> 12);        // / OUT_F
    int col = (int)(idx & (OUT_F - 1));
    const float4* xr = (const float4*)(x + (size_t)row * IN_F);
    const float4* wr = (const float4*)(w + (size_t)col * IN_F);
    const float4* mr = (const float4*)(m + (size_t)col * IN_F);
    float s = 0.f;
    for (int k = 0; k < IN_F / 4; ++k) {
        float4 xv = xr[k], wv = wr[k], mv = mr[k];
        s += xv.x * wv.x * mv.x + xv.y * wv.y * mv.y +
             xv.z * wv.z * mv.z + xv.w * wv.w * mv.w;
    }
    out[idx] = s + bias[col];
}

// ---------- launch ----------

extern "C" void kernel_launch(void* const* d_in, const int* in_sizes, int n_in,
                              void* d_out, int out_size, void* d_ws, size_t ws_size,
                              hipStream_t stream) {
    const float* x    = (const float*)d_in[0];
    const float* w    = (const float*)d_in[1];
    const float* bias = (const float*)d_in[2];
    const float* mask = (const float*)d_in[3];
    float* out = (float*)d_out;

    const size_t need = ((size_t)BATCH * IN_F + (size_t)OUT_F * IN_F) * sizeof(unsigned short);
    if (ws_size < need) {
        fallback_kernel<<<(size_t)BATCH * OUT_F / 256, 256, 0, stream>>>(
            x, w, bias, mask, out);
        return;
    }

    // workspace layout: x_bf16 [BATCH*IN_F] then w_bf16 [OUT_F*IN_F]
    unsigned short* xb = (unsigned short*)d_ws;
    unsigned short* wb = xb + (size_t)BATCH * IN_F;

    cvt_kernel<<<(XF4 + WF4) / 256, 256, 0, stream>>>(
        (const float4*)x, (const float4*)w, (const float4*)mask,
        (uint2*)xb, (uint2*)wb);

    gemm_kernel<<<512, 512, 0, stream>>>(xb, wb, bias, out);
}

// Round 5
// 557.532 us; speedup vs baseline: 1.3442x; 1.0449x over previous
//
#include <hip/hip_runtime.h>
#include <stdint.h>

#define BATCH 8192
#define IN_F  4096
#define OUT_F 4096

#define BM 256
#define BN 256
#define BK 32
#define KT2 (IN_F / BK)        // 128 k-windows
#define ABYTES (BM * BK * 2)   // 16384 B per buffer A region
#define BUFB   (2 * ABYTES)    // 32768 B per buffer (A + B)

typedef __attribute__((ext_vector_type(8))) short bf16x8;   // 8 bf16 = 4 VGPRs
typedef __attribute__((ext_vector_type(4))) float f32x4;    // 16x16 MFMA acc

// ---------- helpers ----------

__device__ __forceinline__ unsigned short f2bf(float f) {
    // round-to-nearest-even bf16 (inputs finite)
    unsigned int u = __float_as_uint(f);
    unsigned int lsb = (u >> 16) & 1u;
    u += 0x7fffu + lsb;
    return (unsigned short)(u >> 16);
}

__device__ __forceinline__ void gl_lds16(const void* g, void* l) {
    // async global->LDS, 16B per lane. HW dest = wave-uniform base + lane*16.
    __builtin_amdgcn_global_load_lds(
        (const __attribute__((address_space(1))) void*)g,
        (__attribute__((address_space(3))) void*)l,
        16, 0, 0);
}

// ---------- fused convert kernel (unit-stride: 1 float4 in, 4 bf16 out) ----------
#define XF4 (BATCH * IN_F / 4)   // 8388608
#define WF4 (OUT_F * IN_F / 4)   // 4194304

__global__ __launch_bounds__(256) void cvt_kernel(const float4* __restrict__ x,
                                                  const float4* __restrict__ w,
                                                  const float4* __restrict__ m,
                                                  uint2* __restrict__ xo,
                                                  uint2* __restrict__ wo) {
    const int i = blockIdx.x * 256 + threadIdx.x;
    union { unsigned short u[4]; uint2 v; } r;
    if (i < XF4) {
        const float4 a = x[i];
        r.u[0] = f2bf(a.x); r.u[1] = f2bf(a.y);
        r.u[2] = f2bf(a.z); r.u[3] = f2bf(a.w);
        xo[i] = r.v;
    } else {
        const int j = i - XF4;
        const float4 a = w[j];
        const float4 b = m[j];
        r.u[0] = f2bf(a.x * b.x); r.u[1] = f2bf(a.y * b.y);
        r.u[2] = f2bf(a.z * b.z); r.u[3] = f2bf(a.w * b.w);
        wo[j] = r.v;
    }
}

// ---------- GEMM: C[M,N] = A[M,K] * W[N,K]^T + bias ----------
// 256x256 tile, BK=32, TRIPLE-buffered LDS (3 x 32 KiB), 8 waves (2Mx4N),
// per-wave 128x64 output, 16x16x32 MFMA.
// Swizzle: stored 16B chunk = logical chunk ^ (row&3) (4 chunks per 64B row)
// -> conflict-free ds_read_b128 (8 lanes per 16B bank-quad = minimum).
// Window W(kt): {READ frags of tile kt+1 from buf[(kt+1)%3];
//                STAGE tile kt+3 -> buf[kt%3];  MFMA tile kt (regs);
//                lgkm0; vmcnt(4); barrier}
// The vmcnt(4) leaves this window's 4 loads in flight and confirms tile kt+2
// (issued 2 windows ago, ~2800 cyc of cover) landed -> NEVER drains to 0 in
// the main loop (T4).  Buffer roles rotate {stage,read,land} <- {read,land,stage}.
__global__ __launch_bounds__(512, 2) void gemm_kernel(const unsigned short* __restrict__ A,
                                                      const unsigned short* __restrict__ W,
                                                      const float* __restrict__ bias,
                                                      float* __restrict__ C) {
    __shared__ unsigned short lds[3 * BUFB / 2];   // 96 KiB

    const int tid  = threadIdx.x;
    const int lane = tid & 63;
    const int wave = tid >> 6;     // 0..7
    const int wm   = wave >> 2;    // 0..1  (M half)
    const int wn   = wave & 3;     // 0..3  (N quarter)

    // XCD-aware swizzle: 512 wgs, 64 contiguous per XCD (bijective)
    const int wg = ((blockIdx.x & 7) << 6) | (blockIdx.x >> 3);
    const int bm = wg >> 4;        // 0..31
    const int bn = wg & 15;        // 0..15

    const int r15 = lane & 15;     // fragment row within 16
    const int g   = lane >> 4;     // k-group 0..3 (8 bf16 each)
    const int cs  = (g ^ (r15 & 3)) << 4;   // stored-chunk byte offset for reads

    // ---- read offsets (bytes within a buffer) ----
    int aoff[8], boff[4];
#pragma unroll
    for (int mf = 0; mf < 8; ++mf)
        aoff[mf] = ((wm * 128 + mf * 16 + r15) << 6) + cs;
#pragma unroll
    for (int nf = 0; nf < 4; ++nf)
        boff[nf] = ABYTES + ((wn * 64 + nf * 16 + r15) << 6) + cs;

    // ---- staging geometry: 4 gl_lds per thread per tile (A x2, B x2) ----
    // slot s = i*512+tid (i=0,1 -> A region; i=2,3 -> B region)
    // row = s>>2, stored chunk = s&3 holds logical chunk (s&3)^(row&3)
    int ldsb[4];                       // LDS byte offset within buffer
    const unsigned short* gA[2];
    const unsigned short* gB[2];
#pragma unroll
    for (int i = 0; i < 4; ++i) {
        const int s    = (i & 1) * 512 + tid;
        const int row  = s >> 2;
        const int chnk = (s & 3) ^ (row & 3);
        ldsb[i] = (i < 2 ? 0 : ABYTES) + s * 16;
        if (i < 2) gA[i]     = A + (size_t)(bm * BM + row) * IN_F + chnk * 8;
        else       gB[i - 2] = W + (size_t)(bn * BN + row) * IN_F + chnk * 8;
    }

    char* ldsc = (char*)lds;

#define STAGE(bufoff, ktn)                                                   \
    do {                                                                     \
        gl_lds16(gA[0] + (ktn) * BK, ldsc + (bufoff) + ldsb[0]);             \
        gl_lds16(gA[1] + (ktn) * BK, ldsc + (bufoff) + ldsb[1]);             \
        gl_lds16(gB[0] + (ktn) * BK, ldsc + (bufoff) + ldsb[2]);             \
        gl_lds16(gB[1] + (ktn) * BK, ldsc + (bufoff) + ldsb[3]);             \
    } while (0)

#define READ(AX, BX, bufoff)                                                 \
    do {                                                                     \
        _Pragma("unroll")                                                    \
        for (int mf = 0; mf < 8; ++mf)                                       \
            AX[mf] = *(const bf16x8*)(ldsc + (bufoff) + aoff[mf]);           \
        _Pragma("unroll")                                                    \
        for (int nf = 0; nf < 4; ++nf)                                       \
            BX[nf] = *(const bf16x8*)(ldsc + (bufoff) + boff[nf]);           \
    } while (0)

#define MFMA_ALL(AX, BX)                                                     \
    do {                                                                     \
        __builtin_amdgcn_s_setprio(1);                                       \
        _Pragma("unroll")                                                    \
        for (int mf = 0; mf < 8; ++mf)                                       \
            _Pragma("unroll")                                                \
            for (int nf = 0; nf < 4; ++nf)                                   \
                acc[mf][nf] = __builtin_amdgcn_mfma_f32_16x16x32_bf16(       \
                    AX[mf], BX[nf], acc[mf][nf], 0, 0, 0);                   \
        __builtin_amdgcn_s_setprio(0);                                       \
    } while (0)

// W(kt): read tile kt+1 from rb, stage tile kt+3 into sb, MFMA tile kt (AC,BC)
#define WINDOW(kt, AC, BC, AN, BN_)                                          \
    do {                                                                     \
        if ((kt) + 1 < KT2) READ(AN, BN_, rb);                               \
        if ((kt) + 3 < KT2) STAGE(sb, (kt) + 3);                             \
        MFMA_ALL(AC, BC);                                                    \
        if ((kt) + 1 < KT2) {                                                \
            asm volatile("s_waitcnt lgkmcnt(0)" ::: "memory");               \
            __builtin_amdgcn_sched_barrier(0);                               \
            if ((kt) + 3 < KT2) { asm volatile("s_waitcnt vmcnt(4)" ::: "memory"); } \
            else                { asm volatile("s_waitcnt vmcnt(0)" ::: "memory"); } \
            __builtin_amdgcn_s_barrier();                                    \
            __builtin_amdgcn_sched_barrier(0);                               \
            int t_ = sb; sb = rb; rb = lb; lb = t_;                          \
        }                                                                    \
    } while (0)

    f32x4 acc[8][4] = {};
    bf16x8 aC[8], bC[4], aN[8], bN[4];

    // ---- prologue: stage tiles 0,1,2 into bufs 0,1,2 (12 loads) ----
    STAGE(0 * BUFB, 0);
    STAGE(1 * BUFB, 1);
    STAGE(2 * BUFB, 2);
    asm volatile("s_waitcnt vmcnt(8)" ::: "memory");   // tile 0 landed
    __builtin_amdgcn_s_barrier();
    __builtin_amdgcn_sched_barrier(0);

    READ(aC, bC, 0 * BUFB);                            // tile 0 -> cur regs
    asm volatile("s_waitcnt lgkmcnt(0)" ::: "memory");
    __builtin_amdgcn_sched_barrier(0);
    asm volatile("s_waitcnt vmcnt(4)" ::: "memory");   // tile 1 landed; tile 2 in flight
    __builtin_amdgcn_s_barrier();
    __builtin_amdgcn_sched_barrier(0);

    int sb = 0 * BUFB, rb = 1 * BUFB, lb = 2 * BUFB;

#pragma unroll 1
    for (int kt = 0; kt < KT2; kt += 2) {
        WINDOW(kt,     aC, bC, aN, bN);
        WINDOW(kt + 1, aN, bN, aC, bC);
    }
#undef WINDOW
#undef MFMA_ALL
#undef READ
#undef STAGE

    // epilogue: 16x16 C/D layout: col = lane&15, row = (lane>>4)*4 + reg
    const int crow0 = bm * BM + wm * 128 + g * 4;
    const int ccol0 = bn * BN + wn * 64 + r15;
#pragma unroll
    for (int nf = 0; nf < 4; ++nf) {
        const int col = ccol0 + nf * 16;
        const float bj = bias[col];
#pragma unroll
        for (int mf = 0; mf < 8; ++mf)
#pragma unroll
            for (int reg = 0; reg < 4; ++reg) {
                const int row = crow0 + mf * 16 + reg;
                C[(size_t)row * OUT_F + col] = acc[mf][nf][reg] + bj;
            }
    }
}

// ---------- fallback (no workspace): correct-but-slow fp32 path ----------
__global__ __launch_bounds__(256) void fallback_kernel(const float* __restrict__ x,
                                                       const float* __restrict__ w,
                                                       const float* __restrict__ bias,
                                                       const float* __restrict__ m,
                                                       float* __restrict__ out) {
    size_t idx = (size_t)blockIdx.x * 256 + threadIdx.x;   // over BATCH*OUT_F
    int row = (int)(idx >> 12);        // / OUT_F
    int col = (int)(idx & (OUT_F - 1));
    const float4* xr = (const float4*)(x + (size_t)row * IN_F);
    const float4* wr = (const float4*)(w + (size_t)col * IN_F);
    const float4* mr = (const float4*)(m + (size_t)col * IN_F);
    float s = 0.f;
    for (int k = 0; k < IN_F / 4; ++k) {
        float4 xv = xr[k], wv = wr[k], mv = mr[k];
        s += xv.x * wv.x * mv.x + xv.y * wv.y * mv.y +
             xv.z * wv.z * mv.z + xv.w * wv.w * mv.w;
    }
    out[idx] = s + bias[col];
}

// ---------- launch ----------

extern "C" void kernel_launch(void* const* d_in, const int* in_sizes, int n_in,
                              void* d_out, int out_size, void* d_ws, size_t ws_size,
                              hipStream_t stream) {
    const float* x    = (const float*)d_in[0];
    const float* w    = (const float*)d_in[1];
    const float* bias = (const float*)d_in[2];
    const float* mask = (const float*)d_in[3];
    float* out = (float*)d_out;

    const size_t need = ((size_t)BATCH * IN_F + (size_t)OUT_F * IN_F) * sizeof(unsigned short);
    if (ws_size < need) {
        fallback_kernel<<<(size_t)BATCH * OUT_F / 256, 256, 0, stream>>>(
            x, w, bias, mask, out);
        return;
    }

    // workspace layout: x_bf16 [BATCH*IN_F] then w_bf16 [OUT_F*IN_F]
    unsigned short* xb = (unsigned short*)d_ws;
    unsigned short* wb = xb + (size_t)BATCH * IN_F;

    cvt_kernel<<<(XF4 + WF4) / 256, 256, 0, stream>>>(
        (const float4*)x, (const float4*)w, (const float4*)mask,
        (uint2*)xb, (uint2*)wb);

    gemm_kernel<<<512, 512, 0, stream>>>(xb, wb, bias, out);
}

// Round 6
// 541.164 us; speedup vs baseline: 1.3849x; 1.0302x over previous
//
#include <hip/hip_runtime.h>
#include <stdint.h>

#define BATCH 8192
#define IN_F  4096
#define OUT_F 4096

#define BM 256
#define BN 256
#define BK 64
#define KT (IN_F / BK)   // 64 k-tiles

typedef __attribute__((ext_vector_type(8))) short bf16x8;   // 8 bf16 = 4 VGPRs
typedef __attribute__((ext_vector_type(4))) float f32x4;    // 16x16 MFMA acc

// ---------- helpers ----------

__device__ __forceinline__ unsigned short f2bf(float f) {
    // round-to-nearest-even bf16 (inputs finite)
    unsigned int u = __float_as_uint(f);
    unsigned int lsb = (u >> 16) & 1u;
    u += 0x7fffu + lsb;
    return (unsigned short)(u >> 16);
}

__device__ __forceinline__ void gl_lds16(const void* g, void* l) {
    // async global->LDS, 16B per lane. HW dest = wave-uniform base + lane*16.
    __builtin_amdgcn_global_load_lds(
        (const __attribute__((address_space(1))) void*)g,
        (__attribute__((address_space(3))) void*)l,
        16, 0, 0);
}

// ---------- fused convert kernel (unit-stride: 1 float4 in, 4 bf16 out) ----------
#define XF4 (BATCH * IN_F / 4)   // 8388608
#define WF4 (OUT_F * IN_F / 4)   // 4194304

__global__ __launch_bounds__(256) void cvt_kernel(const float4* __restrict__ x,
                                                  const float4* __restrict__ w,
                                                  const float4* __restrict__ m,
                                                  uint2* __restrict__ xo,
                                                  uint2* __restrict__ wo) {
    const int i = blockIdx.x * 256 + threadIdx.x;
    union { unsigned short u[4]; uint2 v; } r;
    if (i < XF4) {
        const float4 a = x[i];
        r.u[0] = f2bf(a.x); r.u[1] = f2bf(a.y);
        r.u[2] = f2bf(a.z); r.u[3] = f2bf(a.w);
        xo[i] = r.v;
    } else {
        const int j = i - XF4;
        const float4 a = w[j];
        const float4 b = m[j];
        r.u[0] = f2bf(a.x * b.x); r.u[1] = f2bf(a.y * b.y);
        r.u[2] = f2bf(a.z * b.z); r.u[3] = f2bf(a.w * b.w);
        wo[j] = r.v;
    }
}

// ---------- GEMM: C[M,N] = A[M,K] * W[N,K]^T + bias ----------
// 256x256 tile, BK=64, double-buffered (2 x 64 KiB), 8 waves (2Mx4N),
// per-wave 128x64 output, 16x16x32 MFMA.
// Swizzle (proven conflict-free, rounds 2-3): stored 16B chunk =
// logical chunk ^ (row&7); row stride 128 B.  Bank model (calibrated on
// rounds 1/3/5): bank = 4*(g ^ (r15&7)) + i -> 2 lanes/bank = free.
// Schedule (m201 8-phase template): per K-tile, 4 phases of
//   { ds_read (ph1: B all 8 + A0 4; ph2-4: A pair 4);  2 x gl_lds;
//     [ph1: lgkmcnt(8) hint];  barrier;  lgkm0;  setprio(1) 16 MFMA
//     setprio(0);  [ph2: vmcnt(4); ph4: vmcnt(2)];  barrier }
// Staging spread 2/phase: ph1-2 stage B(kt+1), ph3-4 stage A(kt+1) (A slot
// order s0,s2,s1,s3).  vmcnt ledger (uniform for prologue/steady/tail):
//   ph4-end vmcnt(2): retires B(kt+1)+A(kt+1)s0,s2 (needed next ph1-2),
//                     leaves A(kt+1)s1,s3 in flight;
//   ph2-end vmcnt(4): retires A(kt)s1,s3 (needed ph3-4), leaves B/A(kt+1).
// Never drains to 0 in the main loop (T4); loads get 1.5-3 phases of cover.
__global__ __launch_bounds__(512, 2) void gemm_kernel(const unsigned short* __restrict__ A,
                                                      const unsigned short* __restrict__ W,
                                                      const float* __restrict__ bias,
                                                      float* __restrict__ C) {
    __shared__ __align__(16) char smem[131072];   // A: [0,64K) 2 bufs; B: [64K,128K)
    char* sA = smem;
    char* sB = smem + 65536;

    const int tid  = threadIdx.x;
    const int lane = tid & 63;
    const int wave = tid >> 6;     // 0..7
    const int wm   = wave >> 2;    // 0..1  (M half)
    const int wn   = wave & 3;     // 0..3  (N quarter)

    // XCD-aware swizzle: 512 wgs, 64 contiguous per XCD (bijective)
    const int wg = ((blockIdx.x & 7) << 6) | (blockIdx.x >> 3);
    const int bm = wg >> 4;        // 0..31
    const int bn = wg & 15;        // 0..15

    const int r15 = lane & 15;     // fragment row within 16
    const int g   = lane >> 4;     // k-group 0..3 (8 bf16 each)
    const int k0  = (g ^ (r15 & 7)) << 4;   // stored-chunk byte; ks=1 -> ^64

    // ---- staging geometry: 4 slots/thread per matrix ----
    // slot s = i*512+tid: row = s>>3, stored chunk s&7 holds logical (s&7)^(row&7)
    int ldso[4];
    const unsigned short* gAp[4];
    const unsigned short* gBp[4];
#pragma unroll
    for (int i = 0; i < 4; ++i) {
        const int s   = i * 512 + tid;
        const int row = s >> 3;
        const int ch  = (s & 7) ^ (row & 7);
        ldso[i] = s * 16;
        gAp[i] = A + (size_t)(bm * BM + row) * IN_F + ch * 8;
        gBp[i] = W + (size_t)(bn * BN + row) * IN_F + ch * 8;
    }

#define GLA(buf, ktn, sl) gl_lds16(gAp[sl] + (ktn) * BK, sA + (buf) * 32768 + ldso[sl])
#define GLB(buf, ktn, sl) gl_lds16(gBp[sl] + (ktn) * BK, sB + (buf) * 32768 + ldso[sl])

    f32x4 acc[8][4] = {};
    bf16x8 af[2][2], bgf[4][2];

#define RDA(p)                                                               \
    do {                                                                     \
        _Pragma("unroll")                                                    \
        for (int i = 0; i < 2; ++i)                                          \
            _Pragma("unroll")                                                \
            for (int ks = 0; ks < 2; ++ks)                                   \
                af[i][ks] = *(const bf16x8*)(aB2 + ((p) * 2 + i) * 2048 +    \
                                             (k0 ^ (ks << 6)));              \
    } while (0)
#define RDB()                                                                \
    do {                                                                     \
        _Pragma("unroll")                                                    \
        for (int nf = 0; nf < 4; ++nf)                                       \
            _Pragma("unroll")                                                \
            for (int ks = 0; ks < 2; ++ks)                                   \
                bgf[nf][ks] = *(const bf16x8*)(bB2 + nf * 2048 +             \
                                               (k0 ^ (ks << 6)));            \
    } while (0)
#define MM(p)                                                                \
    do {                                                                     \
        __builtin_amdgcn_s_setprio(1);                                       \
        _Pragma("unroll")                                                    \
        for (int ks = 0; ks < 2; ++ks)                                       \
            _Pragma("unroll")                                                \
            for (int i = 0; i < 2; ++i)                                      \
                _Pragma("unroll")                                            \
                for (int nf = 0; nf < 4; ++nf)                               \
                    acc[(p) * 2 + i][nf] =                                   \
                        __builtin_amdgcn_mfma_f32_16x16x32_bf16(             \
                            af[i][ks], bgf[nf][ks], acc[(p) * 2 + i][nf],    \
                            0, 0, 0);                                        \
        __builtin_amdgcn_s_setprio(0);                                       \
    } while (0)
#define LG0   asm volatile("s_waitcnt lgkmcnt(0)" ::: "memory")
#define SBAR  __builtin_amdgcn_s_barrier()
#define SCH0  __builtin_amdgcn_sched_barrier(0)

    // ---- prologue: tile 0, order B s0-3 then A s0,s2,s1,s3 (ledger order) ----
    GLB(0, 0, 0); GLB(0, 0, 1); GLB(0, 0, 2); GLB(0, 0, 3);
    GLA(0, 0, 0); GLA(0, 0, 2); GLA(0, 0, 1); GLA(0, 0, 3);
    asm volatile("s_waitcnt vmcnt(2)" ::: "memory");   // B0 + A0 s0,s2 landed
    SBAR; SCH0;

#pragma unroll 1
    for (int kt = 0; kt < KT; ++kt) {
        const int buf  = kt & 1;
        const int nb   = buf ^ 1;
        const bool more = (kt + 1 < KT);
        const char* aB2 = sA + buf * 32768 + ((wm * 128 + r15) << 7);
        const char* bB2 = sB + buf * 32768 + ((wn * 64 + r15) << 7);

        // ---- phase 1: B all + A0 ----
        RDB(); RDA(0);
        if (more) { GLB(nb, kt + 1, 0); GLB(nb, kt + 1, 1); }
        asm volatile("s_waitcnt lgkmcnt(8)" ::: "memory");
        SBAR; LG0; SCH0;
        MM(0);
        SCH0; SBAR; SCH0;

        // ---- phase 2: A1 ----
        RDA(1);
        if (more) { GLB(nb, kt + 1, 2); GLB(nb, kt + 1, 3); }
        SBAR; LG0; SCH0;
        MM(1);
        SCH0;
        if (more) { asm volatile("s_waitcnt vmcnt(4)" ::: "memory"); }
        else      { asm volatile("s_waitcnt vmcnt(0)" ::: "memory"); }
        SBAR; SCH0;

        // ---- phase 3: A2 ----
        RDA(2);
        if (more) { GLA(nb, kt + 1, 0); GLA(nb, kt + 1, 2); }
        SBAR; LG0; SCH0;
        MM(2);
        SCH0; SBAR; SCH0;

        // ---- phase 4: A3 ----
        RDA(3);
        if (more) { GLA(nb, kt + 1, 1); GLA(nb, kt + 1, 3); }
        SBAR; LG0; SCH0;
        MM(3);
        SCH0;
        if (more) { asm volatile("s_waitcnt vmcnt(2)" ::: "memory"); }
        SBAR; SCH0;
    }
#undef GLA
#undef GLB
#undef RDA
#undef RDB
#undef MM
#undef LG0
#undef SBAR
#undef SCH0

    // epilogue: 16x16 C/D layout: col = lane&15, row = (lane>>4)*4 + reg
    const int crow0 = bm * BM + wm * 128 + g * 4;
    const int ccol0 = bn * BN + wn * 64 + r15;
#pragma unroll
    for (int nf = 0; nf < 4; ++nf) {
        const int col = ccol0 + nf * 16;
        const float bj = bias[col];
#pragma unroll
        for (int mf = 0; mf < 8; ++mf)
#pragma unroll
            for (int reg = 0; reg < 4; ++reg) {
                const int row = crow0 + mf * 16 + reg;
                C[(size_t)row * OUT_F + col] = acc[mf][nf][reg] + bj;
            }
    }
}

// ---------- fallback (no workspace): correct-but-slow fp32 path ----------
__global__ __launch_bounds__(256) void fallback_kernel(const float* __restrict__ x,
                                                       const float* __restrict__ w,
                                                       const float* __restrict__ bias,
                                                       const float* __restrict__ m,
                                                       float* __restrict__ out) {
    size_t idx = (size_t)blockIdx.x * 256 + threadIdx.x;   // over BATCH*OUT_F
    int row = (int)(idx >> 12);        // / OUT_F
    int col = (int)(idx & (OUT_F - 1));
    const float4* xr = (const float4*)(x + (size_t)row * IN_F);
    const float4* wr = (const float4*)(w + (size_t)col * IN_F);
    const float4* mr = (const float4*)(m + (size_t)col * IN_F);
    float s = 0.f;
    for (int k = 0; k < IN_F / 4; ++k) {
        float4 xv = xr[k], wv = wr[k], mv = mr[k];
        s += xv.x * wv.x * mv.x + xv.y * wv.y * mv.y +
             xv.z * wv.z * mv.z + xv.w * wv.w * mv.w;
    }
    out[idx] = s + bias[col];
}

// ---------- launch ----------

extern "C" void kernel_launch(void* const* d_in, const int* in_sizes, int n_in,
                              void* d_out, int out_size, void* d_ws, size_t ws_size,
                              hipStream_t stream) {
    const float* x    = (const float*)d_in[0];
    const float* w    = (const float*)d_in[1];
    const float* bias = (const float*)d_in[2];
    const float* mask = (const float*)d_in[3];
    float* out = (float*)d_out;

    const size_t need = ((size_t)BATCH * IN_F + (size_t)OUT_F * IN_F) * sizeof(unsigned short);
    if (ws_size < need) {
        fallback_kernel<<<(size_t)BATCH * OUT_F / 256, 256, 0, stream>>>(
            x, w, bias, mask, out);
        return;
    }

    // workspace layout: x_bf16 [BATCH*IN_F] then w_bf16 [OUT_F*IN_F]
    unsigned short* xb = (unsigned short*)d_ws;
    unsigned short* wb = xb + (size_t)BATCH * IN_F;

    cvt_kernel<<<(XF4 + WF4) / 256, 256, 0, stream>>>(
        (const float4*)x, (const float4*)w, (const float4*)mask,
        (uint2*)xb, (uint2*)wb);

    gemm_kernel<<<512, 512, 0, stream>>>(xb, wb, bias, out);
}

// Round 7
// 539.307 us; speedup vs baseline: 1.3897x; 1.0034x over previous
//
#include <hip/hip_runtime.h>
#include <stdint.h>

#define BATCH 8192
#define IN_F  4096
#define OUT_F 4096

#define BM 256
#define BN 256
#define BK 64
#define KT (IN_F / BK)   // 64 k-tiles

typedef __attribute__((ext_vector_type(8))) short bf16x8;   // 8 bf16 = 4 VGPRs
typedef __attribute__((ext_vector_type(4))) float f32x4;    // 16x16 MFMA acc

// ---------- helpers ----------

__device__ __forceinline__ unsigned short f2bf(float f) {
    unsigned int u = __float_as_uint(f);
    unsigned int lsb = (u >> 16) & 1u;
    u += 0x7fffu + lsb;
    return (unsigned short)(u >> 16);
}

__device__ __forceinline__ void gl_lds16(const void* g, void* l) {
    __builtin_amdgcn_global_load_lds(
        (const __attribute__((address_space(1))) void*)g,
        (__attribute__((address_space(3))) void*)l,
        16, 0, 0);
}

// ---------- fused convert kernel (unit-stride) ----------
#define XF4 (BATCH * IN_F / 4)
#define WF4 (OUT_F * IN_F / 4)

__global__ __launch_bounds__(256) void cvt_kernel(const float4* __restrict__ x,
                                                  const float4* __restrict__ w,
                                                  const float4* __restrict__ m,
                                                  uint2* __restrict__ xo,
                                                  uint2* __restrict__ wo) {
    const int i = blockIdx.x * 256 + threadIdx.x;
    union { unsigned short u[4]; uint2 v; } r;
    if (i < XF4) {
        const float4 a = x[i];
        r.u[0] = f2bf(a.x); r.u[1] = f2bf(a.y);
        r.u[2] = f2bf(a.z); r.u[3] = f2bf(a.w);
        xo[i] = r.v;
    } else {
        const int j = i - XF4;
        const float4 a = w[j];
        const float4 b = m[j];
        r.u[0] = f2bf(a.x * b.x); r.u[1] = f2bf(a.y * b.y);
        r.u[2] = f2bf(a.z * b.z); r.u[3] = f2bf(a.w * b.w);
        wo[j] = r.v;
    }
}

// ---------- GEMM: C[M,N] = A[M,K] * W[N,K]^T + bias ----------
// 256x256 tile, BK=64, 8 waves (2Mx4N), per-wave 128x64, 16x16x32 MFMA.
// LDS: 2 A-buffers (2x32K) + 3 B-buffers (3x32K) = 160 KiB exactly.
// Swizzle: stored chunk = logical chunk ^ (row&7) (proven 0-conflict).
// Pipelined phases, ONE barrier per K-tile, every wait COUNTED:
//  ph0: RDA(q1)->afB; GLA(kt+1,s0,s2);      lgkm(4); MFMA(q0: afA)
//  ph1: RDA(q2)->afA; GLA(kt+1,s1,s3);      lgkm(4); MFMA(q1: afB)
//  ph2: RDA(q3)->afB; GLB(kt+2,s0..3);      lgkm(4); MFMA(q2: afA)
//       lgkm(0); vmcnt(4); SBAR       <- retires B(kt+1)(full-tile cover)
//                                        + A(kt+1)(~1-phase, L2-warm);
//                                        leaves B(kt+2)x4 in flight
//  ph3: MFMA(q3: afB);  RDB(kt+1)->bgf; RDA(q0,kt+1)->afA
//       (reads after MM(3): bgf WAR; they overlap MFMA execution and are
//        gated by next tile's ph0 lgkm(4))
// Hazard audit: every restage target's readers complete (lgkm-gated) before
// the single barrier that precedes the restage; B-buf cycles mod 3 so the
// staged buffer is never the current or next tile's B.
__global__ __launch_bounds__(512, 2) void gemm_kernel(const unsigned short* __restrict__ A,
                                                      const unsigned short* __restrict__ W,
                                                      const float* __restrict__ bias,
                                                      float* __restrict__ C) {
    __shared__ __align__(16) char smem[163840];
    char* sA = smem;            // 2 x 32768
    char* sB = smem + 65536;    // 3 x 32768

    const int tid  = threadIdx.x;
    const int lane = tid & 63;
    const int wave = tid >> 6;
    const int wm   = wave >> 2;    // 0..1
    const int wn   = wave & 3;     // 0..3

    const int wg = ((blockIdx.x & 7) << 6) | (blockIdx.x >> 3);
    const int bm = wg >> 4;        // 0..31
    const int bn = wg & 15;        // 0..15

    const int r15 = lane & 15;
    const int g   = lane >> 4;
    const int k0  = (g ^ (r15 & 7)) << 4;   // ks=1 -> ^64

    // staging slots: s = i*512+tid, row = s>>3, stored chunk s&7 holds
    // logical chunk (s&7)^(row&7)
    int ldso[4];
    const unsigned short* gAp[4];
#pragma unroll
    for (int i = 0; i < 4; ++i) {
        const int s   = i * 512 + tid;
        const int row = s >> 3;
        const int ch  = (s & 7) ^ (row & 7);
        ldso[i] = s * 16;
        gAp[i] = A + (size_t)(bm * BM + row) * IN_F + ch * 8;
    }
    // uniform element delta A-slot -> B-slot (same row/chunk geometry)
    const ptrdiff_t bdel = (W + (size_t)bn * BN * IN_F) - (A + (size_t)bm * BM * IN_F);

#define GLA(aoffb, ktn, sl) gl_lds16(gAp[sl] + (ktn) * BK, sA + (aoffb) + ldso[sl])
#define GLB(boffb, ktn, sl) gl_lds16(gAp[sl] + bdel + (ktn) * BK, sB + (boffb) + ldso[sl])

    const int arow = (wm * 128 + r15) << 7;
    const int brow = (wn * 64 + r15) << 7;

    f32x4 acc[8][4] = {};
    bf16x8 afA[2][2], afB[2][2], bgf[4][2];

#define RDA(q, DST, abase)                                                   \
    do {                                                                     \
        _Pragma("unroll")                                                    \
        for (int i = 0; i < 2; ++i)                                          \
            _Pragma("unroll")                                                \
            for (int ks = 0; ks < 2; ++ks)                                   \
                DST[i][ks] = *(const bf16x8*)((abase) +                      \
                    (((q) * 32 + i * 16) << 7) + (k0 ^ (ks << 6)));          \
    } while (0)
#define RDB(bbase)                                                           \
    do {                                                                     \
        _Pragma("unroll")                                                    \
        for (int nf = 0; nf < 4; ++nf)                                       \
            _Pragma("unroll")                                                \
            for (int ks = 0; ks < 2; ++ks)                                   \
                bgf[nf][ks] = *(const bf16x8*)((bbase) + nf * 2048 +         \
                                               (k0 ^ (ks << 6)));            \
    } while (0)
#define MM(p, AX)                                                            \
    do {                                                                     \
        __builtin_amdgcn_s_setprio(1);                                       \
        _Pragma("unroll")                                                    \
        for (int ks = 0; ks < 2; ++ks)                                       \
            _Pragma("unroll")                                                \
            for (int i = 0; i < 2; ++i)                                      \
                _Pragma("unroll")                                            \
                for (int nf = 0; nf < 4; ++nf)                               \
                    acc[(p) * 2 + i][nf] =                                   \
                        __builtin_amdgcn_mfma_f32_16x16x32_bf16(             \
                            AX[i][ks], bgf[nf][ks], acc[(p) * 2 + i][nf],    \
                            0, 0, 0);                                        \
        __builtin_amdgcn_s_setprio(0);                                       \
    } while (0)
#define LGKM4 asm volatile("s_waitcnt lgkmcnt(4)" ::: "memory")
#define LGKM0 asm volatile("s_waitcnt lgkmcnt(0)" ::: "memory")
#define SBAR  __builtin_amdgcn_s_barrier()
#define SCH0  __builtin_amdgcn_sched_barrier(0)

    // ---- prologue: A(0)->Abuf0, B(0)->Bbuf0, B(1)->Bbuf1 (12 loads) ----
    GLA(0, 0, 0); GLA(0, 0, 1); GLA(0, 0, 2); GLA(0, 0, 3);
    GLB(0, 0, 0); GLB(0, 0, 1); GLB(0, 0, 2); GLB(0, 0, 3);
    GLB(32768, 1, 0); GLB(32768, 1, 1); GLB(32768, 1, 2); GLB(32768, 1, 3);
    asm volatile("s_waitcnt vmcnt(4)" ::: "memory");   // A(0),B(0) landed
    SBAR; SCH0;

    RDB(sB + brow);                       // B(0) -> bgf
    RDA(0, afA, sA + arow);               // q0(0) -> afA
    SCH0;

    int bb1 = 32768;   // B-buf[(kt+1)%3] byte offset (read in ph3)
    int bb2 = 65536;   // B-buf[(kt+2)%3] byte offset (stage target ph2)

#pragma unroll 1
    for (int kt = 0; kt < KT; ++kt) {
        const bool m1 = (kt + 1 < KT);
        const bool m2 = (kt + 2 < KT);
        const int  ab  = (kt & 1) << 15;         // current A-buf
        const int  abn = ab ^ 32768;             // next A-buf
        const char* aB  = sA + ab + arow;
        const char* aBn = sA + abn + arow;

        // ---- ph0 ----
        RDA(1, afB, aB);
        if (m1) { GLA(abn, kt + 1, 0); GLA(abn, kt + 1, 2); }
        SCH0; LGKM4; SCH0;
        MM(0, afA);
        SCH0;

        // ---- ph1 ----
        RDA(2, afA, aB);
        if (m1) { GLA(abn, kt + 1, 1); GLA(abn, kt + 1, 3); }
        SCH0; LGKM4; SCH0;
        MM(1, afB);
        SCH0;

        // ---- ph2 ----
        RDA(3, afB, aB);
        if (m2) { GLB(bb2, kt + 2, 0); GLB(bb2, kt + 2, 1);
                  GLB(bb2, kt + 2, 2); GLB(bb2, kt + 2, 3); }
        SCH0; LGKM4; SCH0;
        MM(2, afA);
        SCH0; LGKM0; SCH0;
        if (m2)      { asm volatile("s_waitcnt vmcnt(4)" ::: "memory"); SBAR; }
        else if (m1) { asm volatile("s_waitcnt vmcnt(0)" ::: "memory"); SBAR; }
        SCH0;

        // ---- ph3 ----
        MM(3, afB);
        if (m1) {
            RDB(sB + bb1 + brow);          // B(kt+1) -> bgf (WAR after MM(3))
            RDA(0, afA, aBn);              // q0(kt+1) -> afA
        }
        SCH0;

        bb1 = bb2;
        bb2 += 32768; if (bb2 == 98304) bb2 = 0;
    }
#undef GLA
#undef GLB
#undef RDA
#undef RDB
#undef MM
#undef LGKM4
#undef LGKM0
#undef SBAR
#undef SCH0

    // epilogue: 16x16 C/D layout: col = lane&15, row = (lane>>4)*4 + reg
    const int crow0 = bm * BM + wm * 128 + g * 4;
    const int ccol0 = bn * BN + wn * 64 + r15;
#pragma unroll
    for (int nf = 0; nf < 4; ++nf) {
        const int col = ccol0 + nf * 16;
        const float bj = bias[col];
#pragma unroll
        for (int mf = 0; mf < 8; ++mf)
#pragma unroll
            for (int reg = 0; reg < 4; ++reg) {
                const int row = crow0 + mf * 16 + reg;
                C[(size_t)row * OUT_F + col] = acc[mf][nf][reg] + bj;
            }
    }
}

// ---------- fallback (no workspace): correct-but-slow fp32 path ----------
__global__ __launch_bounds__(256) void fallback_kernel(const float* __restrict__ x,
                                                       const float* __restrict__ w,
                                                       const float* __restrict__ bias,
                                                       const float* __restrict__ m,
                                                       float* __restrict__ out) {
    size_t idx = (size_t)blockIdx.x * 256 + threadIdx.x;
    int row = (int)(idx >> 12);
    int col = (int)(idx & (OUT_F - 1));
    const float4* xr = (const float4*)(x + (size_t)row * IN_F);
    const float4* wr = (const float4*)(w + (size_t)col * IN_F);
    const float4* mr = (const float4*)(m + (size_t)col * IN_F);
    float s = 0.f;
    for (int k = 0; k < IN_F / 4; ++k) {
        float4 xv = xr[k], wv = wr[k], mv = mr[k];
        s += xv.x * wv.x * mv.x + xv.y * wv.y * mv.y +
             xv.z * wv.z * mv.z + xv.w * wv.w * mv.w;
    }
    out[idx] = s + bias[col];
}

// ---------- launch ----------

extern "C" void kernel_launch(void* const* d_in, const int* in_sizes, int n_in,
                              void* d_out, int out_size, void* d_ws, size_t ws_size,
                              hipStream_t stream) {
    const float* x    = (const float*)d_in[0];
    const float* w    = (const float*)d_in[1];
    const float* bias = (const float*)d_in[2];
    const float* mask = (const float*)d_in[3];
    float* out = (float*)d_out;

    const size_t need = ((size_t)BATCH * IN_F + (size_t)OUT_F * IN_F) * sizeof(unsigned short);
    if (ws_size < need) {
        fallback_kernel<<<(size_t)BATCH * OUT_F / 256, 256, 0, stream>>>(
            x, w, bias, mask, out);
        return;
    }

    unsigned short* xb = (unsigned short*)d_ws;
    unsigned short* wb = xb + (size_t)BATCH * IN_F;

    cvt_kernel<<<(XF4 + WF4) / 256, 256, 0, stream>>>(
        (const float4*)x, (const float4*)w, (const float4*)mask,
        (uint2*)xb, (uint2*)wb);

    gemm_kernel<<<512, 512, 0, stream>>>(xb, wb, bias, out);
}